// Round 14
// baseline (42.435 us; speedup 1.0000x reference)
//
#include <hip/hip_runtime.h>
#include <math.h>

#define LN_EPS 1e-5f

// Problem constants (fixed by setup_inputs): N=10, K=5, Q=5, H=256, Qtot=50
constexpr int Nn  = 10;
constexpr int Kk  = 5;
constexpr int Hh  = 256;
constexpr int QT  = 50;
constexpr int QH  = 25;   // QT/2: queries per group-slot in C/F
constexpr int NP1 = 11;

// ---------- DPP-based reductions (VALU pipe; zero DS-pipe ops) ----------
template<int CTRL, int RM>
__device__ __forceinline__ float dpp_term(float x) {
    return __int_as_float(__builtin_amdgcn_update_dpp(
        0, __float_as_int(x), CTRL, RM, 0xf, true));   // bound_ctrl: OOB -> 0
}
// broadcast sum across each 16-lane group (4 DPP adds)
__device__ __forceinline__ float sum16_bcast(float v) {
    v += dpp_term<0xB1,  0xf>(v);   // quad_perm [1,0,3,2]
    v += dpp_term<0x4E,  0xf>(v);   // quad_perm [2,3,0,1]
    v += dpp_term<0x124, 0xf>(v);   // row_ror:4
    v += dpp_term<0x128, 0xf>(v);   // row_ror:8 -> full 16-sum, all lanes
    return v;
}
// wave sum accumulated into lane 63 (6 DPP adds)
__device__ __forceinline__ float sum64_lane63(float v) {
    v += dpp_term<0x111, 0xf>(v);   // row_shr:1
    v += dpp_term<0x112, 0xf>(v);   // row_shr:2
    v += dpp_term<0x114, 0xf>(v);   // row_shr:4
    v += dpp_term<0x118, 0xf>(v);   // row_shr:8
    v += dpp_term<0x142, 0xa>(v);   // row_bcast:15 -> rows 1,3
    v += dpp_term<0x143, 0xc>(v);   // row_bcast:31 -> rows 2,3 (lane63 = total)
    return v;
}
__device__ __forceinline__ float rdlane(float v, int l) {
    return __int_as_float(__builtin_amdgcn_readlane(__float_as_int(v), l));
}
__device__ __forceinline__ float wave64_sum_bcast(float v) {
    return rdlane(sum64_lane63(v), 63);
}

// One batch per 1024-thread block (16 waves). 3 barriers.
// A  (waves 0-9):  support stream: LN inline (sstat->LDS), M->MP_s, ||M||^2,
//                  support scores.
// A' (waves 10-15): query stream (2-deep load pipeline): LN stats, LN'd y ->
//                  qy_s. (ny moved to C -> A/A' chain counts balanced ~16 each.)
// C  (groups 0-24, TWO queries each: q, q+25): y from qy_s, ny->LDS, dots vs
//                  M with each M row fragment read ONCE per n and reused for
//                  both queries (DS-pipe fix #2: C/F ds_read_b128 halved),
//                  argmin(nM-2p), wq/cq/counts.
//     B (groups 56-60): per-k softmax over N of support scores.
// E  (waves 0-9):  rectified prototype; ballot loop reads qy_s; proto -> MP_s.
// F  (groups 0-24, TWO queries each): dots vs proto, d=ny+np-2p, logits+pred.
// LDS ~63KB/block -> 2 blocks/CU. NOTE: nothing register-live across barriers.
__global__ __launch_bounds__(1024, 8) void proto_rectify_fused(
    const float* __restrict__ support, const float* __restrict__ query,
    const float* __restrict__ gamma,   const float* __restrict__ beta,
    float* __restrict__ out, int B)
{
    const int b    = blockIdx.x;
    const int tid  = threadIdx.x;
    const int lane = tid & 63;
    const int wave = tid >> 6;   // 0..15
    const int grp  = tid >> 4;   // 0..63
    const int sub  = tid & 15;

    __shared__ float qy_s[QT][Hh];        // LN'd query rows (51.2 KB)
    __shared__ float MP_s[Nn][Hh];        // M (A-C), then proto (E-F)
    __shared__ float nM_s[Nn], np_s[Nn];
    __shared__ float ny_s[QT];
    __shared__ float score_s[Nn * Kk];
    __shared__ float wsup_s[Nn * Kk];
    __shared__ float wq_s[QT];
    __shared__ int   cq_s[QT];
    __shared__ float sstat_s[Nn * Kk][2]; // support row: mu, rstd
    __shared__ int   cnt_s[Nn];

    const float* supB = support + (size_t)b * (Nn * Kk * Hh);
    const float* qryB = query   + (size_t)b * (QT * Hh);

    if (tid < Nn) cnt_s[tid] = 0;

    // ---------------- Phase A / A' ----------------
    const float4 g4 = *reinterpret_cast<const float4*>(gamma + lane * 4);  // L1
    const float4 b4 = *reinterpret_cast<const float4*>(beta  + lane * 4);
    if (wave < Nn) {
        const int n = wave;
        const float* rows = supB + (size_t)n * Kk * Hh;

        float y[Kk][4];
#pragma unroll
        for (int k = 0; k < Kk; ++k) {
            const float4 x = *reinterpret_cast<const float4*>(rows + k * Hh + lane * 4);
            float s  = x.x + x.y + x.z + x.w;
            float ss = x.x * x.x + x.y * x.y + x.z * x.z + x.w * x.w;
            s  = wave64_sum_bcast(s);
            ss = wave64_sum_bcast(ss);
            const float mu   = s * (1.0f / (float)Hh);
            const float rstd = rsqrtf(ss * (1.0f / (float)Hh) - mu * mu + LN_EPS);
            if (lane == 0) { sstat_s[n * Kk + k][0] = mu; sstat_s[n * Kk + k][1] = rstd; }
            y[k][0] = (x.x - mu) * rstd * g4.x + b4.x;
            y[k][1] = (x.y - mu) * rstd * g4.y + b4.y;
            y[k][2] = (x.z - mu) * rstd * g4.z + b4.z;
            y[k][3] = (x.w - mu) * rstd * g4.w + b4.w;
        }
        float Mv[4];
#pragma unroll
        for (int i = 0; i < 4; ++i)
            Mv[i] = (y[0][i] + y[1][i] + y[2][i] + y[3][i] + y[4][i]) / 5.0f;
        *reinterpret_cast<float4*>(&MP_s[n][lane * 4]) =
            make_float4(Mv[0], Mv[1], Mv[2], Mv[3]);

        float pm = Mv[0] * Mv[0];
        pm = fmaf(Mv[1], Mv[1], pm); pm = fmaf(Mv[2], Mv[2], pm); pm = fmaf(Mv[3], Mv[3], pm);
        pm = sum64_lane63(pm);
        if (lane == 63) nM_s[n] = pm;

#pragma unroll
        for (int k = 0; k < Kk; ++k) {
            float p = y[k][0] * Mv[0];
            p = fmaf(y[k][1], Mv[1], p); p = fmaf(y[k][2], Mv[2], p); p = fmaf(y[k][3], Mv[3], p);
            p = sum64_lane63(p);
            if (lane == 63) score_s[n * Kk + k] = p;
        }
    } else {
        // A': waves 10-15 stream + LN query rows into qy_s (2-deep pipeline)
        int r = wave - 10;
        float4 x = make_float4(0.f, 0.f, 0.f, 0.f);
        if (r < QT) x = *reinterpret_cast<const float4*>(qryB + (size_t)r * Hh + lane * 4);
        while (r < QT) {
            const int rn = r + 6;
            float4 xn = x;
            if (rn < QT)                       // issue next load before chains
                xn = *reinterpret_cast<const float4*>(qryB + (size_t)rn * Hh + lane * 4);
            float s  = x.x + x.y + x.z + x.w;
            float ss = fmaf(x.x, x.x, fmaf(x.y, x.y, fmaf(x.z, x.z, x.w * x.w)));
            s  = wave64_sum_bcast(s);
            ss = wave64_sum_bcast(ss);
            const float mu   = s * (1.0f / (float)Hh);
            const float rstd = rsqrtf(ss * (1.0f / (float)Hh) - mu * mu + LN_EPS);
            *reinterpret_cast<float4*>(&qy_s[r][lane * 4]) = make_float4(
                (x.x - mu) * rstd * g4.x + b4.x,
                (x.y - mu) * rstd * g4.y + b4.y,
                (x.z - mu) * rstd * g4.z + b4.z,
                (x.w - mu) * rstd * g4.w + b4.w);
            x = xn; r = rn;
        }
    }
    __syncthreads();

    // ---------------- C (groups 0-24, dual query) + B (groups 56-60) ---------
    if (grp < QH) {
        const int q0 = grp, q1 = grp + QH;
        const float nmv = (lane < Nn) ? nM_s[lane] : 0.f;   // hoist ||M||^2
        float ya[16], yb[16];
#pragma unroll
        for (int c = 0; c < 4; ++c) {
            const float4 va = *reinterpret_cast<const float4*>(&qy_s[q0][c * 64 + sub * 4]);
            ya[c * 4 + 0] = va.x; ya[c * 4 + 1] = va.y;
            ya[c * 4 + 2] = va.z; ya[c * 4 + 3] = va.w;
            const float4 vb = *reinterpret_cast<const float4*>(&qy_s[q1][c * 64 + sub * 4]);
            yb[c * 4 + 0] = vb.x; yb[c * 4 + 1] = vb.y;
            yb[c * 4 + 2] = vb.z; yb[c * 4 + 3] = vb.w;
        }
        // ny for both queries (moved here from A'; 4 ILP chains + sum16)
        {
            float a0 = 0.f, a1 = 0.f, b0 = 0.f, b1 = 0.f;
#pragma unroll
            for (int j = 0; j < 8; ++j) {
                a0 = fmaf(ya[j], ya[j], a0);
                a1 = fmaf(ya[j + 8], ya[j + 8], a1);
                b0 = fmaf(yb[j], yb[j], b0);
                b1 = fmaf(yb[j + 8], yb[j + 8], b1);
            }
            const float nya = sum16_bcast(a0 + a1);
            const float nyb = sum16_bcast(b0 + b1);
            if (sub == 0) { ny_s[q0] = nya; ny_s[q1] = nyb; }
        }
        float bestdA = INFINITY, bestdotA = 0.f; int bestnA = 0;
        float bestdB = INFINITY, bestdotB = 0.f; int bestnB = 0;
#pragma unroll
        for (int n = 0; n < Nn; ++n) {
            // read M row fragment ONCE, use for both queries
            const float4 m0 = *reinterpret_cast<const float4*>(&MP_s[n][0 * 64 + sub * 4]);
            const float4 m1 = *reinterpret_cast<const float4*>(&MP_s[n][1 * 64 + sub * 4]);
            const float4 m2 = *reinterpret_cast<const float4*>(&MP_s[n][2 * 64 + sub * 4]);
            const float4 m3 = *reinterpret_cast<const float4*>(&MP_s[n][3 * 64 + sub * 4]);
            float pa = ya[0] * m0.x;  float pb = yb[0] * m0.x;
            pa = fmaf(ya[1],  m0.y, pa); pb = fmaf(yb[1],  m0.y, pb);
            pa = fmaf(ya[2],  m0.z, pa); pb = fmaf(yb[2],  m0.z, pb);
            pa = fmaf(ya[3],  m0.w, pa); pb = fmaf(yb[3],  m0.w, pb);
            pa = fmaf(ya[4],  m1.x, pa); pb = fmaf(yb[4],  m1.x, pb);
            pa = fmaf(ya[5],  m1.y, pa); pb = fmaf(yb[5],  m1.y, pb);
            pa = fmaf(ya[6],  m1.z, pa); pb = fmaf(yb[6],  m1.z, pb);
            pa = fmaf(ya[7],  m1.w, pa); pb = fmaf(yb[7],  m1.w, pb);
            pa = fmaf(ya[8],  m2.x, pa); pb = fmaf(yb[8],  m2.x, pb);
            pa = fmaf(ya[9],  m2.y, pa); pb = fmaf(yb[9],  m2.y, pb);
            pa = fmaf(ya[10], m2.z, pa); pb = fmaf(yb[10], m2.z, pb);
            pa = fmaf(ya[11], m2.w, pa); pb = fmaf(yb[11], m2.w, pb);
            pa = fmaf(ya[12], m3.x, pa); pb = fmaf(yb[12], m3.x, pb);
            pa = fmaf(ya[13], m3.y, pa); pb = fmaf(yb[13], m3.y, pb);
            pa = fmaf(ya[14], m3.z, pa); pb = fmaf(yb[14], m3.z, pb);
            pa = fmaf(ya[15], m3.w, pa); pb = fmaf(yb[15], m3.w, pb);
            pa = sum16_bcast(pa);        pb = sum16_bcast(pb);
            const float nm = rdlane(nmv, n);
            const float da = nm - 2.0f * pa;   // argmin drops ny (const per q)
            const float db = nm - 2.0f * pb;
            if (da < bestdA) { bestdA = da; bestnA = n; bestdotA = pa; }
            if (db < bestdB) { bestdB = db; bestnB = n; bestdotB = pb; }
        }
        if (sub == 0) {
            {
                const float mx  = fmaxf(bestdotA, 0.f);
                const float e   = expf(bestdotA - mx);
                const float den = e + (float)(Nn - 1) * expf(-mx);
                wq_s[q0] = e / den;  cq_s[q0] = bestnA;
                atomicAdd(&cnt_s[bestnA], 1);
            }
            {
                const float mx  = fmaxf(bestdotB, 0.f);
                const float e   = expf(bestdotB - mx);
                const float den = e + (float)(Nn - 1) * expf(-mx);
                wq_s[q1] = e / den;  cq_s[q1] = bestnB;
                atomicAdd(&cnt_s[bestnB], 1);
            }
        }
    } else if (grp >= 56 && grp < 56 + Kk && sub == 0) {
        const int k = grp - 56;
        float mx = -INFINITY;
#pragma unroll
        for (int n = 0; n < Nn; ++n) mx = fmaxf(mx, score_s[n * Kk + k]);
        float e[Nn]; float den = 0.f;
#pragma unroll
        for (int n = 0; n < Nn; ++n) { e[n] = expf(score_s[n * Kk + k] - mx); den += e[n]; }
#pragma unroll
        for (int n = 0; n < Nn; ++n) wsup_s[n * Kk + k] = e[n] / den;
    }
    __syncthreads();

    // ---------------- E (waves 0-9): rectified prototype -> MP_s -------------
    if (wave < Nn) {
        const int n = wave;
        const float* rows = supB + (size_t)n * Kk * Hh;

        float acc[4] = {0.f, 0.f, 0.f, 0.f};
#pragma unroll
        for (int k = 0; k < Kk; ++k) {
            const float w    = wsup_s[n * Kk + k];
            const float mu   = sstat_s[n * Kk + k][0];
            const float rstd = sstat_s[n * Kk + k][1];
            const float4 x = *reinterpret_cast<const float4*>(rows + k * Hh + lane * 4);
            acc[0] = fmaf(w, (x.x - mu) * rstd * g4.x + b4.x, acc[0]);
            acc[1] = fmaf(w, (x.y - mu) * rstd * g4.y + b4.y, acc[1]);
            acc[2] = fmaf(w, (x.z - mu) * rstd * g4.z + b4.z, acc[2]);
            acc[3] = fmaf(w, (x.w - mu) * rstd * g4.w + b4.w, acc[3]);
        }
        // ballot-compressed query rectification; LN'd y read from qy_s (LDS)
        int myc = -1; float myw = 0.f;
        if (lane < QT) { myc = cq_s[lane]; myw = wq_s[lane]; }
        unsigned long long mask = __ballot(lane < QT && myc == n);
        while (mask) {
            const int q = __ffsll(mask) - 1;
            mask &= mask - 1;
            const float w = rdlane(myw, q);
            const float4 yv = *reinterpret_cast<const float4*>(&qy_s[q][lane * 4]);
            acc[0] = fmaf(w, yv.x, acc[0]);
            acc[1] = fmaf(w, yv.y, acc[1]);
            acc[2] = fmaf(w, yv.z, acc[2]);
            acc[3] = fmaf(w, yv.w, acc[3]);
        }
        const float inv = 1.0f / (float)(Kk + cnt_s[n]);
        float pv[4];
#pragma unroll
        for (int i = 0; i < 4; ++i) pv[i] = acc[i] * inv;
        *reinterpret_cast<float4*>(&MP_s[n][lane * 4]) =      // proto overwrites M
            make_float4(pv[0], pv[1], pv[2], pv[3]);
        float pp = pv[0] * pv[0];
        pp = fmaf(pv[1], pv[1], pp); pp = fmaf(pv[2], pv[2], pp); pp = fmaf(pv[3], pv[3], pp);
        pp = sum64_lane63(pp);
        if (lane == 63) np_s[n] = pp;
    }
    __syncthreads();

    // ---------------- F (groups 0-24, dual query): logits + pred -------------
    if (grp < QH) {
        const int q0 = grp, q1 = grp + QH;
        const float npv = (lane < Nn) ? np_s[lane] : 0.f;    // hoist ||p||^2
        float ya[16], yb[16];
#pragma unroll
        for (int c = 0; c < 4; ++c) {
            const float4 va = *reinterpret_cast<const float4*>(&qy_s[q0][c * 64 + sub * 4]);
            ya[c * 4 + 0] = va.x; ya[c * 4 + 1] = va.y;
            ya[c * 4 + 2] = va.z; ya[c * 4 + 3] = va.w;
            const float4 vb = *reinterpret_cast<const float4*>(&qy_s[q1][c * 64 + sub * 4]);
            yb[c * 4 + 0] = vb.x; yb[c * 4 + 1] = vb.y;
            yb[c * 4 + 2] = vb.z; yb[c * 4 + 3] = vb.w;
        }
        const float nya = ny_s[q0], nyb = ny_s[q1];

        float mineA = 0.f, maxdA = -INFINITY, bestdA = INFINITY; int bestnA = 0;
        float mineB = 0.f, maxdB = -INFINITY, bestdB = INFINITY; int bestnB = 0;
#pragma unroll
        for (int n = 0; n < Nn; ++n) {
            const float4 m0 = *reinterpret_cast<const float4*>(&MP_s[n][0 * 64 + sub * 4]);
            const float4 m1 = *reinterpret_cast<const float4*>(&MP_s[n][1 * 64 + sub * 4]);
            const float4 m2 = *reinterpret_cast<const float4*>(&MP_s[n][2 * 64 + sub * 4]);
            const float4 m3 = *reinterpret_cast<const float4*>(&MP_s[n][3 * 64 + sub * 4]);
            float pa = ya[0] * m0.x;  float pb = yb[0] * m0.x;
            pa = fmaf(ya[1],  m0.y, pa); pb = fmaf(yb[1],  m0.y, pb);
            pa = fmaf(ya[2],  m0.z, pa); pb = fmaf(yb[2],  m0.z, pb);
            pa = fmaf(ya[3],  m0.w, pa); pb = fmaf(yb[3],  m0.w, pb);
            pa = fmaf(ya[4],  m1.x, pa); pb = fmaf(yb[4],  m1.x, pb);
            pa = fmaf(ya[5],  m1.y, pa); pb = fmaf(yb[5],  m1.y, pb);
            pa = fmaf(ya[6],  m1.z, pa); pb = fmaf(yb[6],  m1.z, pb);
            pa = fmaf(ya[7],  m1.w, pa); pb = fmaf(yb[7],  m1.w, pb);
            pa = fmaf(ya[8],  m2.x, pa); pb = fmaf(yb[8],  m2.x, pb);
            pa = fmaf(ya[9],  m2.y, pa); pb = fmaf(yb[9],  m2.y, pb);
            pa = fmaf(ya[10], m2.z, pa); pb = fmaf(yb[10], m2.z, pb);
            pa = fmaf(ya[11], m2.w, pa); pb = fmaf(yb[11], m2.w, pb);
            pa = fmaf(ya[12], m3.x, pa); pb = fmaf(yb[12], m3.x, pb);
            pa = fmaf(ya[13], m3.y, pa); pb = fmaf(yb[13], m3.y, pb);
            pa = fmaf(ya[14], m3.z, pa); pb = fmaf(yb[14], m3.z, pb);
            pa = fmaf(ya[15], m3.w, pa); pb = fmaf(yb[15], m3.w, pb);
            pa = sum16_bcast(pa);        pb = sum16_bcast(pb);
            const float np = rdlane(npv, n);
            const float da = nya + np - 2.0f * pa;
            const float db = nyb + np - 2.0f * pb;
            if (sub == n) { mineA = da; mineB = db; }   // cndmask, d group-uniform
            maxdA = fmaxf(maxdA, da);
            maxdB = fmaxf(maxdB, db);
            if (da < bestdA) { bestdA = da; bestnA = n; }
            if (db < bestdB) { bestdB = db; bestnB = n; }
        }
        if (sub == Nn) { mineA = -maxdA - 1.0f; mineB = -maxdB - 1.0f; }
        else           { mineA = -mineA;        mineB = -mineB; }
        float* o0 = out + ((size_t)b * QT + q0) * NP1;
        float* o1 = out + ((size_t)b * QT + q1) * NP1;
        if (sub <= Nn) { o0[sub] = mineA; o1[sub] = mineB; }
        if (sub == Nn + 1) {
            out[(size_t)B * QT * NP1 + (size_t)b * QT + q0] = (float)bestnA;
            out[(size_t)B * QT * NP1 + (size_t)b * QT + q1] = (float)bestnB;
        }
    }
}

extern "C" void kernel_launch(void* const* d_in, const int* in_sizes, int n_in,
                              void* d_out, int out_size, void* d_ws, size_t ws_size,
                              hipStream_t stream) {
    const float* support = (const float*)d_in[0];
    const float* query   = (const float*)d_in[1];
    const float* gamma   = (const float*)d_in[2];
    const float* beta    = (const float*)d_in[3];
    float* out = (float*)d_out;

    const int B = in_sizes[0] / (Nn * Kk * Hh);   // 512
    proto_rectify_fused<<<B, 1024, 0, stream>>>(support, query, gamma, beta, out, B);
}